// Round 13
// baseline (175.267 us; speedup 1.0000x reference)
//
#include <hip/hip_runtime.h>
#include <hip/hip_bf16.h>

#define KDIM 4096
#define NKT 128                  // K-tiles of 32
#define NELEM16 (1u << 24)

typedef float f32x4 __attribute__((ext_vector_type(4)));
typedef short bf16x8 __attribute__((ext_vector_type(8)));

typedef const __attribute__((address_space(1))) unsigned int g_u32;
typedef __attribute__((address_space(3))) unsigned int l_u32;

__device__ __forceinline__ void gload_lds16(const void* g, void* l) {
    __builtin_amdgcn_global_load_lds((g_u32*)g, (l_u32*)l, 16, 0, 0);
}

__device__ __forceinline__ unsigned int pack_bf16x2(float lo, float hi) {
    __hip_bfloat162 h = __float22bfloat162_rn(float2{lo, hi});
    union { __hip_bfloat162 h; unsigned int u; } c; c.h = h; return c.u;
}

// ---- pack ----
// A-image (x): [mt16][kt128][rl256][cp4][8e], content x[mt*256+rl][kt*32+(cp^(rl&3))*8..]
// B-image (W): [nt32][kt128][rl128][cp4][8e], content W[nt*128+rl][kt*32+(cp^(rl&3))*8..]
// (XOR swizzle baked into global image; LDS staging stays linear; ds_read applies XOR)
__global__ __launch_bounds__(256)
void pack3(const float* __restrict__ x, const float* __restrict__ W,
           unsigned short* __restrict__ xb, unsigned short* __restrict__ wb)
{
    const unsigned int stride = gridDim.x * blockDim.x;
    for (unsigned int i = blockIdx.x * blockDim.x + threadIdx.x; i < (1u << 22); i += stride) {
        const float* __restrict__ in;
        unsigned short* __restrict__ out;
        unsigned int row, col, j;
        if (i < (1u << 21)) {                    // A-image
            j = i;
            const unsigned int cp = j & 3;
            const unsigned int rl = (j >> 2) & 255;
            const unsigned int kt = (j >> 10) & 127;
            const unsigned int mt = j >> 17;
            row = mt * 256 + rl;
            col = kt * 32 + (cp ^ (rl & 3)) * 8;
            in = x; out = xb;
        } else {                                 // B-image
            j = i - (1u << 21);
            const unsigned int cp = j & 3;
            const unsigned int rl = (j >> 2) & 127;
            const unsigned int kt = (j >> 9) & 127;
            const unsigned int nt = j >> 16;
            row = nt * 128 + rl;
            col = kt * 32 + (cp ^ (rl & 3)) * 8;
            in = W; out = wb;
        }
        const float4* sp = (const float4*)(in + (size_t)row * KDIM + col);
        const float4 a = sp[0], b = sp[1];
        uint4 o;
        o.x = pack_bf16x2(a.x, a.y); o.y = pack_bf16x2(a.z, a.w);
        o.z = pack_bf16x2(b.x, b.y); o.w = pack_bf16x2(b.z, b.w);
        *(uint4*)(out + (size_t)j * 8) = o;
    }
}

// ---- 256x128 GEMM, BK=32, tri-buffer LDS, 2 blocks/CU ----
// LDS elems: buf*12288 + {A: row*32 + swz  |  B: 8192 + row*32 + swz}
#define STAGE3(kt, BUFE)                                                        \
    {                                                                           \
        const unsigned short* ga = Abase + (size_t)(kt) * 8192 + wid * 1024 + lane * 8; \
        gload_lds16(ga,       &lds[(BUFE) + wid * 1024]);                       \
        gload_lds16(ga + 512, &lds[(BUFE) + wid * 1024 + 512]);                 \
        const unsigned short* gb = Bbase + (size_t)(kt) * 4096 + wid * 512 + lane * 8;  \
        gload_lds16(gb,       &lds[(BUFE) + 8192 + wid * 512]);                 \
    }

#define READ_AB(BUFE)                                                           \
    _Pragma("unroll") for (int mf = 0; mf < 4; ++mf)                            \
        afr[mf] = *(const bf16x8*)&lds[(BUFE) + rdA + mf * 512];                \
    _Pragma("unroll") for (int nf = 0; nf < 4; ++nf)                            \
        bfr[nf] = *(const bf16x8*)&lds[(BUFE) + rdB + nf * 512];

#define MFMA16()                                                                \
    __builtin_amdgcn_s_setprio(1);                                              \
    _Pragma("unroll") for (int mf = 0; mf < 4; ++mf)                            \
      _Pragma("unroll") for (int nf = 0; nf < 4; ++nf)                          \
        acc[mf][nf] = __builtin_amdgcn_mfma_f32_16x16x32_bf16(                  \
            afr[mf], bfr[nf], acc[mf][nf], 0, 0, 0);                            \
    __builtin_amdgcn_s_setprio(0);

// phase(t): [reads(t); MFMA(t); stage(t+2)->buf (t+2)%3; vmcnt(3); BAR]
// WAR: stage(t+2) hits the buf whose reads(t-1) were reg-drained before BAR(t-1),
//      and the stager passed BAR(t-1) first. RAW: vmcnt(3) at end of t-1 drains
//      stage(t) (exactly stage(t+1)'s 3 ops are newer); BAR publishes cross-wave.
#define PHASE(t, BUFE, STGE, VMW)                                               \
    {                                                                           \
        READ_AB(BUFE);                                                          \
        MFMA16();                                                               \
        if ((t) + 2 < NKT) STAGE3((t) + 2, STGE);                               \
        VMW;                                                                    \
        __builtin_amdgcn_s_barrier();                                           \
        __builtin_amdgcn_sched_barrier(0);                                      \
    }

#define VM3 asm volatile("s_waitcnt vmcnt(3)" ::: "memory")
#define VM0 asm volatile("s_waitcnt vmcnt(0)" ::: "memory")

__global__ __launch_bounds__(512, 4)
void gemm_cores(const unsigned short* __restrict__ A,
                const unsigned short* __restrict__ B,
                const float* __restrict__ bias,
                float* __restrict__ out)
{
    __shared__ unsigned short lds[36864];   // 72 KiB: 3 bufs x (A 16KB + B 8KB)

    const int tid  = threadIdx.x;
    const int lane = tid & 63;
    const int wid  = tid >> 6;     // 0..7
    const int wm   = wid >> 1;     // 0..3 (64-row slab)
    const int wn   = wid & 1;      // 0..1 (64-col slab)
    const int c15  = lane & 15;
    const int q4   = lane >> 4;

    // 512 blocks = 16(m) x 32(n) tiles; XCD-bijective swizzle (512 % 8 == 0)
    const int bid = blockIdx.x;
    const int wg  = (bid & 7) * 64 + (bid >> 3);
    const int bm  = wg >> 5;       // 0..15
    const int bn  = wg & 31;       // 0..31

    const unsigned short* Abase = A + ((size_t)bm << 20);   // 16KB/kt * 128
    const unsigned short* Bbase = B + ((size_t)bn << 19);   // 8KB/kt * 128

    const int swz = ((q4 ^ (c15 & 3)) * 8);
    const int rdA = (wm * 64 + c15) * 32 + swz;
    const int rdB = 8192 + (wn * 64 + c15) * 32 + swz;

    f32x4 acc[4][4];
    #pragma unroll
    for (int i = 0; i < 4; ++i)
        #pragma unroll
        for (int j = 0; j < 4; ++j)
            acc[i][j] = (f32x4)0.0f;

    bf16x8 afr[4], bfr[4];

    // prologue: tiles 0,1 -> bufs 0,1
    STAGE3(0, 0);
    STAGE3(1, 12288);
    VM3;                       // drains tile0's 3 ops; tile1's 3 in flight
    __builtin_amdgcn_s_barrier();
    __builtin_amdgcn_sched_barrier(0);

    for (int tt = 0; tt < 126; tt += 3) {
        PHASE(tt,     0,     24576, VM3);
        PHASE(tt + 1, 12288, 0,     VM3);
        PHASE(tt + 2, 24576, 12288, VM3);
    }
    PHASE(126, 0, 24576, VM0);     // no stage issued (guard), drain tile127
    // phase 127 (buf 1): reads + MFMA only
    READ_AB(12288);
    MFMA16();

    // Epilogue: bias + maxpool(4 along col) + sum + atomic row add.
    // C/D frag: col = c15, row = q4*4 + r. Wave cols: (nf+wn*4)*16 + c15.
    float rs[4][4];
    #pragma unroll
    for (int mf = 0; mf < 4; ++mf)
        #pragma unroll
        for (int r = 0; r < 4; ++r)
            rs[mf][r] = 0.0f;

    #pragma unroll
    for (int nf = 0; nf < 4; ++nf) {
        const float bv = bias[bn * 128 + wn * 64 + nf * 16 + c15];
        #pragma unroll
        for (int mf = 0; mf < 4; ++mf) {
            #pragma unroll
            for (int r = 0; r < 4; ++r) {
                float v = acc[mf][nf][r] + bv;
                v = fmaxf(v, __shfl_xor(v, 1));
                v = fmaxf(v, __shfl_xor(v, 2));
                v += __shfl_xor(v, 4);
                v += __shfl_xor(v, 8);
                rs[mf][r] += v;
            }
        }
    }

    if (c15 == 0) {
        #pragma unroll
        for (int mf = 0; mf < 4; ++mf)
            #pragma unroll
            for (int r = 0; r < 4; ++r) {
                const int row = bm * 256 + wm * 64 + mf * 16 + q4 * 4 + r;
                atomicAdd(&out[row], 0.5f * rs[mf][r]);
            }
    }
}

// ---------------- fallback (round-1 kernel, verified) if d_ws too small ----------------
__global__ __launch_bounds__(256, 2)
void fused_gemm_pool_fallback(const float* __restrict__ x,
                              const float* __restrict__ W,
                              const float* __restrict__ b,
                              float* __restrict__ out)
{
    __shared__ unsigned short As[128][72];
    __shared__ unsigned short Bs[128][72];

    const int tid  = threadIdx.x;
    const int lane = tid & 63;
    const int wid  = tid >> 6;
    const int wm   = wid >> 1;
    const int wn   = wid & 1;

    const int bid = blockIdx.x;
    const int wg  = (bid & 7) * 128 + (bid >> 3);
    const int bm  = wg >> 5;
    const int bn  = wg & 31;

    const int srow = tid >> 4;
    const int scol = tid & 15;

    const float* xbase = x + (size_t)(bm * 128 + srow) * KDIM + scol * 4;
    const float* wbase = W + (size_t)(bn * 128 + srow) * KDIM + scol * 4;

    f32x4 acc[4][4];
    #pragma unroll
    for (int i = 0; i < 4; ++i)
        #pragma unroll
        for (int j = 0; j < 4; ++j)
            acc[i][j] = (f32x4)0.0f;

    float4 ra[8], rb[8];
    #pragma unroll
    for (int p = 0; p < 8; ++p) {
        ra[p] = *(const float4*)(xbase + (size_t)(p * 16) * KDIM);
        rb[p] = *(const float4*)(wbase + (size_t)(p * 16) * KDIM);
    }

    for (int kt = 0; kt < KDIM / 64; ++kt) {
        #pragma unroll
        for (int p = 0; p < 8; ++p) {
            const int r = srow + p * 16;
            uint2 pa, pb;
            pa.x = pack_bf16x2(ra[p].x, ra[p].y);
            pa.y = pack_bf16x2(ra[p].z, ra[p].w);
            pb.x = pack_bf16x2(rb[p].x, rb[p].y);
            pb.y = pack_bf16x2(rb[p].z, rb[p].w);
            *(uint2*)&As[r][scol * 4] = pa;
            *(uint2*)&Bs[r][scol * 4] = pb;
        }
        __syncthreads();

        if (kt + 1 < KDIM / 64) {
            const float* xa = xbase + (size_t)(kt + 1) * 64;
            const float* wa = wbase + (size_t)(kt + 1) * 64;
            #pragma unroll
            for (int p = 0; p < 8; ++p) {
                ra[p] = *(const float4*)(xa + (size_t)(p * 16) * KDIM);
                rb[p] = *(const float4*)(wa + (size_t)(p * 16) * KDIM);
            }
        }

        #pragma unroll
        for (int k0 = 0; k0 < 2; ++k0) {
            const int kk = k0 * 32 + (lane >> 4) * 8;
            bf16x8 af[4], bfr[4];
            #pragma unroll
            for (int mf = 0; mf < 4; ++mf)
                af[mf] = *(const bf16x8*)&As[wm * 64 + mf * 16 + (lane & 15)][kk];
            #pragma unroll
            for (int nf = 0; nf < 4; ++nf)
                bfr[nf] = *(const bf16x8*)&Bs[wn * 64 + nf * 16 + (lane & 15)][kk];
            #pragma unroll
            for (int mf = 0; mf < 4; ++mf)
                #pragma unroll
                for (int nf = 0; nf < 4; ++nf)
                    acc[mf][nf] = __builtin_amdgcn_mfma_f32_16x16x32_bf16(
                        af[mf], bfr[nf], acc[mf][nf], 0, 0, 0);
        }
        __syncthreads();
    }

    float rs[4][4];
    #pragma unroll
    for (int mf = 0; mf < 4; ++mf)
        #pragma unroll
        for (int r = 0; r < 4; ++r)
            rs[mf][r] = 0.0f;

    #pragma unroll
    for (int nf = 0; nf < 4; ++nf) {
        const float bv = b[bn * 128 + wn * 64 + nf * 16 + (lane & 15)];
        #pragma unroll
        for (int mf = 0; mf < 4; ++mf) {
            #pragma unroll
            for (int r = 0; r < 4; ++r) {
                float v = acc[mf][nf][r] + bv;
                v = fmaxf(v, __shfl_xor(v, 1));
                v = fmaxf(v, __shfl_xor(v, 2));
                v += __shfl_xor(v, 4);
                v += __shfl_xor(v, 8);
                rs[mf][r] += v;
            }
        }
    }

    if ((lane & 15) == 0) {
        #pragma unroll
        for (int mf = 0; mf < 4; ++mf)
            #pragma unroll
            for (int r = 0; r < 4; ++r) {
                const int row = bm * 128 + wm * 64 + mf * 16 + (lane >> 4) * 4 + r;
                atomicAdd(&out[row], 0.5f * rs[mf][r]);
            }
    }
}

extern "C" void kernel_launch(void* const* d_in, const int* in_sizes, int n_in,
                              void* d_out, int out_size, void* d_ws, size_t ws_size,
                              hipStream_t stream) {
    const float* x = (const float*)d_in[0];
    const float* W = (const float*)d_in[1];
    const float* b = (const float*)d_in[2];
    float* out = (float*)d_out;

    hipMemsetAsync(out, 0, (size_t)out_size * sizeof(float), stream);

    const size_t need = (size_t)NELEM16 * 2 * sizeof(unsigned short); // 64 MB
    if (ws_size >= need) {
        unsigned short* xb = (unsigned short*)d_ws;
        unsigned short* wb = xb + (size_t)NELEM16;
        pack3<<<dim3(2048), dim3(256), 0, stream>>>(x, W, xb, wb);
        gemm_cores<<<dim3(512), dim3(512), 0, stream>>>(xb, wb, b, out);
    } else {
        fused_gemm_pool_fallback<<<dim3(1024), dim3(256), 0, stream>>>(x, W, b, out);
    }
}